// Round 7
// baseline (1318.714 us; speedup 1.0000x reference)
//
#include <hip/hip_runtime.h>
#include <hip/hip_bf16.h>
#include <math.h>

// RTM identities:
//  - softmax over size-1 axis == 1  =>  q,k,Wq,Wk dead; newV == v
//  - token j restarts from s0[:,j]; only cumV couples tokens
//  - prefix-sum linear => fold Wv into Wo: Wvo[a] = Wo[a] @ Wv[a] (once);
//       S1 = PS(LN1(T)) @ Wvo[a]^T + T
// Structure ledger (fc1-class, serialized rocprof):
//   gemm_k 128x128 2-buf        50.7 us  (R0, end-to-end 1249 = best)
//   ring-4 256^2 counted-vmcnt  42.2 us  (R2 kernel — best per-kernel)
//   BN=64 6-blk/CU              46.9 us  (R3)
//   8-phase m201 port           72.3 us  (R6 — NT=12 too short to amortize)
// R7: recombine — fc1 = R2's verified ring kernel; fc2/S1/T0/reduce = exact R0.

using bf16   = __bf16;
using bf16x8 = __attribute__((ext_vector_type(8))) __bf16;
using f32x4  = __attribute__((ext_vector_type(4))) float;

#define DEV __device__ __forceinline__

DEV void gload16(const bf16* g, bf16* l) {
  __builtin_amdgcn_global_load_lds(
      (const __attribute__((address_space(1))) unsigned int*)g,
      (__attribute__((address_space(3))) unsigned int*)l, 16, 0, 0);
}

// GELU with A&S 7.1.26 erf (abs err 1.5e-7; << bf16 rounding).
DEV float gelu_f(float x) {
  const float y  = x * 0.70710678118654752f;
  const float ay = fabsf(y);
  const float t  = __builtin_amdgcn_rcpf(__builtin_fmaf(0.3275911f, ay, 1.0f));
  float p = __builtin_fmaf(1.061405429f, t, -1.453152027f);
  p = __builtin_fmaf(p, t, 1.421413741f);
  p = __builtin_fmaf(p, t, -0.284496736f);
  p = __builtin_fmaf(p, t, 0.254829592f);
  p = p * t;
  const float e = __expf(-ay * ay);
  float er = __builtin_fmaf(-p, e, 1.0f);
  er = __builtin_copysignf(er, y);
  return 0.5f * x * (1.0f + er);
}

enum { EPI_PART = 0, EPI_GELU = 1, EPI_B16 = 2 };

// ---------------------------------------------------------------------------
// R2's 256x256-tile deep-pipelined GEMM (verified correct in R2).
// 512 threads = 8 waves (2 row x 4 col), per-wave output 128x64.
// LDS: 4-deep ring of K=32 tiles (A and B, 16 KB each) = 128 KiB.
// Rotate swizzle within each 64 B row -> 2-way bank floor on ds_read_b128;
// staging pre-swizzles the GLOBAL source (LDS dest linear, rule #21).
// Schedule per K-tile t (2 phases), counted vmcnt (never 0 mid-loop):
//   p0: ds_read A-half0 + B | stage A(t+3) | bar | prio1 16 MFMA prio0 | bar
//   p1: ds_read A-half1     | stage B(t+3) | bar | prio1 16 MFMA prio0 |
//       vmcnt(8) [tile t+1 landed; t+2,t+3 in flight] | bar
// ---------------------------------------------------------------------------
template <int EPI>
__global__ __launch_bounds__(512, 2) void gemm256(
    const bf16* __restrict__ A, const bf16* __restrict__ B,
    float* __restrict__ outF, bf16* __restrict__ outB,
    const float* __restrict__ aux, int K, int N,
    int kZ, int klen, size_t oZ)
{
  constexpr int TBUF = 256 * 32;              // 8192 bf16 = 16 KB / matrix / buffer
  __shared__ bf16 As[4 * TBUF];
  __shared__ bf16 Bs[4 * TBUF];
  const int z = blockIdx.z;
  const int kbeg = z * kZ;
  const int tid = threadIdx.x, lane = tid & 63, w = tid >> 6;
  const int wr = w >> 2, wc = w & 3;

  // XCD-chunked bijective tile remap (nwg % 8 == 0 for our grid: 192).
  const int nx = gridDim.x;
  const int nwg = nx * (int)gridDim.y;
  int f = blockIdx.x + nx * blockIdx.y;
  f = (f & 7) * (nwg >> 3) + (f >> 3);
  const int m0 = (f % nx) * 256, n0 = (f / nx) * 256;

  // Staging: thread tid covers row r = tid>>2 (and r+128), slot tid&3.
  // Global chunk kq = ((tid&3) - (r>>1)) & 3 — permutation within a 64 B line.
  const int r  = tid >> 2;
  const int kq = ((tid & 3) - (tid >> 3)) & 3;
  const bf16* aG0 = A + (size_t)(m0 + r) * K + kq * 8 + kbeg;
  const bf16* aG1 = aG0 + (size_t)128 * K;
  const bf16* bG0 = B + (size_t)(n0 + r) * K + kq * 8 + kbeg;
  const bf16* bG1 = bG0 + (size_t)128 * K;

  const int lr = lane & 15, kb = lane >> 4;
  const int swz   = ((kb + (lr >> 1)) & 3) * 8;
  const int aBase = (wr * 128 + lr) * 32 + swz;   // + phase*2048 + g*512
  const int bBase = (wc * 64 + lr) * 32 + swz;    // + nt*512

  f32x4 acc[8][4] = {};
  const int NT = klen >> 5;

  auto stageA = [&](int buf, int t) {
    bf16* d = &As[buf * TBUF + tid * 8];
    gload16(aG0 + t * 32, d);
    gload16(aG1 + t * 32, d + 4096);
  };
  auto stageB = [&](int buf, int t) {
    bf16* d = &Bs[buf * TBUF + tid * 8];
    gload16(bG0 + t * 32, d);
    gload16(bG1 + t * 32, d + 4096);
  };

  // Prologue: 3 tiles in flight; wait only for tile 0 (counted).
  stageA(0, 0); stageB(0, 0);
  if (NT > 1) { stageA(1, 1); stageB(1, 1); }
  if (NT > 2) { stageA(2, 2); stageB(2, 2); }
  if (NT > 2)      asm volatile("s_waitcnt vmcnt(8)" ::: "memory");
  else if (NT > 1) asm volatile("s_waitcnt vmcnt(4)" ::: "memory");
  else             asm volatile("s_waitcnt vmcnt(0)" ::: "memory");
  __builtin_amdgcn_s_barrier();
  asm volatile("" ::: "memory");

  for (int t = 0; t < NT; ++t) {
    const int pa = (t & 3) * TBUF;
    bf16x8 af[4], bfv[4];
    // ---- phase 0: A rows wr*128 + [0,64), all four B col-groups ----
#pragma unroll
    for (int g = 0; g < 4; ++g) af[g] = *(const bf16x8*)&As[pa + aBase + g * 512];
#pragma unroll
    for (int nt = 0; nt < 4; ++nt) bfv[nt] = *(const bf16x8*)&Bs[pa + bBase + nt * 512];
    if (t + 3 < NT) stageA((t + 3) & 3, t + 3);   // into ring slot freed at t-1
    asm volatile("" ::: "memory");
    __builtin_amdgcn_s_barrier();
    asm volatile("" ::: "memory");
    __builtin_amdgcn_s_setprio(1);
#pragma unroll
    for (int g = 0; g < 4; ++g)
#pragma unroll
      for (int nt = 0; nt < 4; ++nt)
        acc[g][nt] = __builtin_amdgcn_mfma_f32_16x16x32_bf16(af[g], bfv[nt], acc[g][nt], 0, 0, 0);
    __builtin_amdgcn_s_setprio(0);
    asm volatile("" ::: "memory");
    __builtin_amdgcn_s_barrier();
    asm volatile("" ::: "memory");
    // ---- phase 1: A rows wr*128 + [64,128), reuse bfv ----
#pragma unroll
    for (int g = 0; g < 4; ++g) af[g] = *(const bf16x8*)&As[pa + aBase + 2048 + g * 512];
    if (t + 3 < NT) stageB((t + 3) & 3, t + 3);
    asm volatile("" ::: "memory");
    __builtin_amdgcn_s_barrier();
    asm volatile("" ::: "memory");
    __builtin_amdgcn_s_setprio(1);
#pragma unroll
    for (int g = 0; g < 4; ++g)
#pragma unroll
      for (int nt = 0; nt < 4; ++nt)
        acc[4 + g][nt] = __builtin_amdgcn_mfma_f32_16x16x32_bf16(af[g], bfv[nt], acc[4 + g][nt], 0, 0, 0);
    __builtin_amdgcn_s_setprio(0);
    // Counted wait: tile t+1 landed; keep t+2 (4) and t+3 (4) in flight.
    if (t + 3 < NT)      asm volatile("s_waitcnt vmcnt(8)" ::: "memory");
    else if (t + 2 < NT) asm volatile("s_waitcnt vmcnt(4)" ::: "memory");
    else if (t + 1 < NT) asm volatile("s_waitcnt vmcnt(0)" ::: "memory");
    asm volatile("" ::: "memory");
    __builtin_amdgcn_s_barrier();
    asm volatile("" ::: "memory");
  }

  // C/D layout: col = lane&15, row = (lane>>4)*4 + reg  [verified m89/m91]
  const int row0 = m0 + wr * 128 + (lane >> 4) * 4;
  const int col0 = n0 + wc * 64 + lr;
  float* oF = (EPI == EPI_PART) ? outF + (size_t)z * oZ : nullptr;
#pragma unroll
  for (int mt = 0; mt < 8; ++mt) {
#pragma unroll
    for (int nt = 0; nt < 4; ++nt) {
      const int col = col0 + nt * 16;
      float bias = 0.f;
      if (EPI == EPI_GELU) bias = aux[col];
#pragma unroll
      for (int rg = 0; rg < 4; ++rg) {
        const int row = row0 + mt * 16 + rg;
        float v = acc[mt][nt][rg];
        if (EPI == EPI_PART) {
          oF[(size_t)row * N + col] = v;
        } else {
          outB[(size_t)row * N + col] = (bf16)gelu_f(v + bias);
        }
      }
    }
  }
}

// ---- 128xBN-tile GEMM — exact R0-proven 2-buf loop --------------------------
template <int BN, int EPI>
__global__ __launch_bounds__(256) void gemm_k(
    const bf16* __restrict__ A, const bf16* __restrict__ B,
    float* __restrict__ outF, bf16* __restrict__ outB,
    const float* __restrict__ aux, int K, int N,
    int kZ, int klen, size_t aZ, size_t bZ, size_t oZ)
{
  constexpr int ABUF = 128 * 32;
  constexpr int BBUF = BN * 32;
  __shared__ bf16 Asl[2 * ABUF];
  __shared__ bf16 Bsl[2 * BBUF];
  const int z = blockIdx.z;
  A += (size_t)z * aZ;
  B += (size_t)z * bZ;
  const int kbeg = z * kZ;
  const int tid  = threadIdx.x;
  const int lane = tid & 63, wave = tid >> 6;
  const int m0 = blockIdx.x * 128, n0 = blockIdx.y * BN;

  const int r  = tid >> 2;
  const int kq = ((tid & 3) - (tid >> 3)) & 3;
  const bf16* aG0 = A + (size_t)(m0 + r) * K + kq * 8 + kbeg;
  const bf16* aG1 = aG0 + (size_t)64 * K;
  const bf16* bG0 = B + (size_t)(n0 + r) * K + kq * 8 + kbeg;
  const bf16* bG1 = bG0 + (size_t)64 * K;   // used only for BN==128

  const int wr = (wave & 1) * 64, wc = (wave >> 1) * (BN / 2);
  const int lr = lane & 15, kb = lane >> 4;
  const int swz  = ((kb + (lr >> 1)) & 3) * 8;
  const int aOff = (wr + lr) * 32 + swz;
  const int bOff = (wc + lr) * 32 + swz;

  constexpr int MT = 4, NTT = BN / 32;
  f32x4 acc[MT][NTT] = {};
  const int iters = klen >> 5;

  auto stage = [&](int p, int k0) {
    bf16* aD = &Asl[p * ABUF + tid * 8];
    gload16(aG0 + k0, aD);
    gload16(aG1 + k0, aD + 2048);
    bf16* bD = &Bsl[p * BBUF + tid * 8];
    gload16(bG0 + k0, bD);
    if (BN == 128) gload16(bG1 + k0, bD + 2048);
  };

  stage(0, 0);
  for (int it = 0; it < iters; ++it) {
    __syncthreads();
    if (it + 1 < iters) stage((it + 1) & 1, (it + 1) * 32);
    const int pa = (it & 1) * ABUF, pb = (it & 1) * BBUF;
    bf16x8 af[MT], bfv[NTT];
#pragma unroll
    for (int t = 0; t < MT; ++t) af[t] = *(const bf16x8*)&Asl[pa + aOff + t * 512];
#pragma unroll
    for (int t = 0; t < NTT; ++t) bfv[t] = *(const bf16x8*)&Bsl[pb + bOff + t * 512];
#pragma unroll
    for (int mt = 0; mt < MT; ++mt)
#pragma unroll
      for (int nt = 0; nt < NTT; ++nt)
        acc[mt][nt] = __builtin_amdgcn_mfma_f32_16x16x32_bf16(af[mt], bfv[nt], acc[mt][nt], 0, 0, 0);
  }

  const int row0 = m0 + wr + (lane >> 4) * 4;
  const int col0 = n0 + wc + lr;
  float* oF = (EPI == EPI_PART) ? outF + (size_t)z * oZ : nullptr;
  bf16*  oB = (EPI == EPI_B16)  ? outB + (size_t)z * oZ : outB;
#pragma unroll
  for (int mt = 0; mt < MT; ++mt) {
#pragma unroll
    for (int nt = 0; nt < NTT; ++nt) {
      const int col = col0 + nt * 16;
      float bias = 0.f;
      if (EPI == EPI_GELU) bias = aux[col];
#pragma unroll
      for (int rg = 0; rg < 4; ++rg) {
        const int row = row0 + mt * 16 + rg;
        float v = acc[mt][nt][rg];
        if (EPI == EPI_PART) {
          oF[(size_t)row * N + col] = v;
        } else if (EPI == EPI_GELU) {
          oB[(size_t)row * N + col] = (bf16)gelu_f(v + bias);
        } else {
          oB[(size_t)row * N + col] = (bf16)v;
        }
      }
    }
  }
}

// One 768-row per block; sums NP split-K partials, adds per-MODE term, LN-fuses.
// MODE 0: s = Σp + PE[row&255]; T=s; SN = LN1(s)
// MODE 1: s = Σp + add[row]   ; SN = LN2(s)+s
// MODE 2: s = Σp + bias       ; T=s; SN = LN1(s)
// MODE 3: s = Σp + bias       ; T=s (fp32 out only, last stage)
template <int NP, int MODE>
__global__ __launch_bounds__(256) void reduce_ln(
    const float* __restrict__ P, size_t pZ,
    const float* __restrict__ add, const float* __restrict__ g,
    const float* __restrict__ b, float* __restrict__ Tout,
    bf16* __restrict__ SNout)
{
  const int row = blockIdx.x, t = threadIdx.x;
  float v[3];
#pragma unroll
  for (int c = 0; c < 3; ++c) {
    const int col = t + c * 256;
    float s = P[(size_t)row * 768 + col];
#pragma unroll
    for (int p = 1; p < NP; ++p) s += P[(size_t)p * pZ + (size_t)row * 768 + col];
    if (MODE == 0) s += add[(row & 255) * 768 + col];
    if (MODE == 1) s += add[(size_t)row * 768 + col];
    if (MODE == 2 || MODE == 3) s += add[col];
    v[c] = s;
  }
  if (MODE != 1) {
#pragma unroll
    for (int c = 0; c < 3; ++c) Tout[(size_t)row * 768 + t + c * 256] = v[c];
  }
  if (MODE == 3) return;

  __shared__ float red[8];
  float s = v[0] + v[1] + v[2];
#pragma unroll
  for (int o = 32; o >= 1; o >>= 1) s += __shfl_down(s, o);
  if ((t & 63) == 0) red[t >> 6] = s;
  __syncthreads();
  const float mu = (red[0] + red[1] + red[2] + red[3]) * (1.f / 768.f);
  const float d0 = v[0] - mu, d1 = v[1] - mu, d2 = v[2] - mu;
  float q = d0 * d0 + d1 * d1 + d2 * d2;
#pragma unroll
  for (int o = 32; o >= 1; o >>= 1) q += __shfl_down(q, o);
  if ((t & 63) == 0) red[4 + (t >> 6)] = q;
  __syncthreads();
  const float var = (red[4] + red[5] + red[6] + red[7]) * (1.f / 768.f);
  const float rs = rsqrtf(var + 1e-5f);
  float y0 = d0 * rs * g[t] + b[t];
  float y1 = d1 * rs * g[t + 256] + b[t + 256];
  float y2 = d2 * rs * g[t + 512] + b[t + 512];
  if (MODE == 1) { y0 += v[0]; y1 += v[1]; y2 += v[2]; }
  bf16* o = SNout + (size_t)row * 768;
  o[t] = (bf16)y0; o[t + 256] = (bf16)y1; o[t + 512] = (bf16)y2;
}

// Exclusive prefix over token axis j (256 tokens) of SN[n,j,d], bf16 io.
__global__ __launch_bounds__(256) void scan_partial_b(
    const bf16* __restrict__ SN, float* __restrict__ Ps)
{
  const int n = blockIdx.x, ch = blockIdx.y, d = blockIdx.z * 256 + threadIdx.x;
  const bf16* base = SN + ((size_t)(n * 256 + ch * 16)) * 768 + d;
  float s = 0.f;
#pragma unroll
  for (int j = 0; j < 16; ++j) s += (float)base[(size_t)j * 768];
  Ps[(size_t)(n * 16 + ch) * 768 + d] = s;
}

__global__ __launch_bounds__(256) void scan_final_b(
    const bf16* __restrict__ SN, const float* __restrict__ Ps,
    bf16* __restrict__ PSb)
{
  const int n = blockIdx.x, ch = blockIdx.y, d = blockIdx.z * 256 + threadIdx.x;
  float run = 0.f;
  for (int c = 0; c < ch; ++c) run += Ps[(size_t)(n * 16 + c) * 768 + d];
  const bf16* vb = SN + ((size_t)(n * 256 + ch * 16)) * 768 + d;
  bf16* ob = PSb + ((size_t)(n * 256 + ch * 16)) * 768 + d;
#pragma unroll
  for (int j = 0; j < 16; ++j) {
    ob[(size_t)j * 768] = (bf16)run;
    run += (float)vb[(size_t)j * 768];
  }
}

// WvT[a][n][k] = (bf16)Wv[a][k][n]; 64x64 tiles via LDS (65-float stride).
__global__ __launch_bounds__(256) void transpose_wv(
    const float* __restrict__ Wv, bf16* __restrict__ WvT)
{
  __shared__ float tile[64][65];
  const int a = blockIdx.z, k0 = blockIdx.x * 64, n0 = blockIdx.y * 64;
  const int c = threadIdx.x & 63, r4 = threadIdx.x >> 6;
  const float* src = Wv + (size_t)a * 589824;
  bf16* dst = WvT + (size_t)a * 589824;
#pragma unroll
  for (int i = 0; i < 16; ++i)
    tile[r4 + i * 4][c] = src[(size_t)(k0 + r4 + i * 4) * 768 + n0 + c];
  __syncthreads();
#pragma unroll
  for (int i = 0; i < 16; ++i) {
    const int n = r4 + i * 4;
    dst[(size_t)(n0 + n) * 768 + k0 + c] = (bf16)tile[c][n];
  }
}

__global__ __launch_bounds__(256) void f32_to_bf16_k(
    const float* __restrict__ in, bf16* __restrict__ out, int n4)
{
  const int i = blockIdx.x * 256 + threadIdx.x;
  if (i >= n4) return;
  const float4 v = ((const float4*)in)[i];
  bf16 h[4] = {(bf16)v.x, (bf16)v.y, (bf16)v.z, (bf16)v.w};
  *(uint2*)(out + 4 * (size_t)i) = *(uint2*)h;
}

// pe[j, 2p] = sin(j / 10000^(4p/768)),  pe[j, 2p+1] = cos(...)
__global__ __launch_bounds__(256) void pe_kernel(float* __restrict__ PE)
{
  const int id = blockIdx.x * 256 + threadIdx.x;  // 256*384 total
  const int j = id / 384, p = id % 384;
  const double ang = (double)j * pow(10000.0, -4.0 * (double)p / 768.0);
  PE[(size_t)j * 768 + 2 * p]     = (float)sin(ang);
  PE[(size_t)j * 768 + 2 * p + 1] = (float)cos(ang);
}

extern "C" void kernel_launch(void* const* d_in, const int* in_sizes, int n_in,
                              void* d_out, int out_size, void* d_ws, size_t ws_size,
                              hipStream_t stream)
{
  const float* x      = (const float*)d_in[0];
  const float* weight = (const float*)d_in[1];
  const float* Wv     = (const float*)d_in[4];
  const float* Wo     = (const float*)d_in[5];
  const float* ln1g   = (const float*)d_in[6];
  const float* ln1b   = (const float*)d_in[7];
  const float* ln2g   = (const float*)d_in[8];
  const float* ln2b   = (const float*)d_in[9];
  const float* fc1w   = (const float*)d_in[10];
  const float* fc1b   = (const float*)d_in[11];
  const float* fc2w   = (const float*)d_in[12];
  const float* fc2b   = (const float*)d_in[13];
  float* out = (float*)d_out;

  char* p = (char*)d_ws;
  auto alloc = [&](size_t bytes) { char* r = p; p += (bytes + 255) & ~(size_t)255; return r; };
  bf16*  Wb_w  = (bf16*)alloc(589824ull * 2);
  bf16*  Wb_o  = (bf16*)alloc(5898240ull * 2);
  bf16*  WvT   = (bf16*)alloc(5898240ull * 2);
  bf16*  Wvo   = (bf16*)alloc(5898240ull * 2);
  bf16*  Wb_f1 = (bf16*)alloc(2359296ull * 2);
  bf16*  Wb_f2 = (bf16*)alloc(2359296ull * 2);
  bf16*  Xb    = (bf16*)alloc(3145728ull * 2);
  float* PEf   = (float*)alloc(196608ull * 4);
  float* T     = (float*)alloc(3145728ull * 4);
  bf16*  SN    = (bf16*)alloc(3145728ull * 2);
  bf16*  PSb   = (bf16*)alloc(3145728ull * 2);
  bf16*  H     = (bf16*)alloc(12582912ull * 2);
  float* Ps    = (float*)alloc(196608ull * 4);
  float* Part  = (float*)alloc(2ull * 3145728ull * 4);

  auto cvt = [&](const float* src, bf16* dst, int n) {
    int n4 = n / 4;
    f32_to_bf16_k<<<(n4 + 255) / 256, 256, 0, stream>>>(src, dst, n4);
  };
  cvt(x, Xb, 3145728);
  cvt(weight, Wb_w, 589824);
  cvt(Wo, Wb_o, 5898240);
  cvt(fc1w, Wb_f1, 2359296);
  cvt(fc2w, Wb_f2, 2359296);
  transpose_wv<<<dim3(12, 12, 10), 256, 0, stream>>>(Wv, WvT);
  pe_kernel<<<384, 256, 0, stream>>>(PEf);

  // Wvo[a] = Wo[a] @ Wv[a]  (A = Wo[a][m,t], B = WvT[a][k,t], batched over z)
  gemm_k<128, EPI_B16><<<dim3(6, 6, 10), 256, 0, stream>>>(
      Wb_o, WvT, nullptr, Wvo, nullptr, 768, 768, 0, 768, 589824, 589824, 589824);

  // T0 = x @ weight^T + PE (split-K x2, 128x64 tiles), fused LN1
  gemm_k<64, EPI_PART><<<dim3(32, 12, 2), 256, 0, stream>>>(
      Xb, Wb_w, Part, nullptr, nullptr, 768, 768, 384, 384, 0, 0, 3145728);
  reduce_ln<2, 0><<<4096, 256, 0, stream>>>(Part, 3145728, PEf, ln1g, ln1b, T, SN);

  for (int a = 0; a < 10; ++a) {
    scan_partial_b<<<dim3(16, 16, 3), 256, 0, stream>>>(SN, Ps);
    scan_final_b<<<dim3(16, 16, 3), 256, 0, stream>>>(SN, Ps, PSb);
    // S1 partials = PS @ Wvo[a]^T  (split-K x2, 128x64 tiles)
    gemm_k<64, EPI_PART><<<dim3(32, 12, 2), 256, 0, stream>>>(
        PSb, Wvo + (size_t)a * 589824, Part, nullptr, nullptr, 768, 768, 384, 384, 0, 0, 3145728);
    reduce_ln<2, 1><<<4096, 256, 0, stream>>>(Part, 3145728, T, ln2g, ln2b, nullptr, SN);
    // fc1: H = gelu(SN2 @ fc1w^T + b) — R2 ring-4 counted-vmcnt 256x256
    gemm256<EPI_GELU><<<dim3(16, 12, 1), 512, 0, stream>>>(
        SN, Wb_f1, nullptr, H, fc1b, 768, 3072, 0, 768, 0);
    // fc2 partials: H @ fc2w^T — exact R0: split-K x2, 128x64 tiles
    gemm_k<64, EPI_PART><<<dim3(32, 12, 2), 256, 0, stream>>>(
        H, Wb_f2, Part, nullptr, nullptr, 3072, 768, 1536, 1536, 0, 0, 3145728);
    if (a < 9)
      reduce_ln<2, 2><<<4096, 256, 0, stream>>>(Part, 3145728, fc2b, ln1g, ln1b, T, SN);
    else
      reduce_ln<2, 3><<<4096, 256, 0, stream>>>(Part, 3145728, fc2b, nullptr, nullptr, out, nullptr);
  }
  (void)in_sizes; (void)n_in; (void)out_size; (void)ws_size;
}

// Round 8
// 1212.816 us; speedup vs baseline: 1.0873x; 1.0873x over previous
//
#include <hip/hip_runtime.h>
#include <hip/hip_bf16.h>
#include <math.h>

// RTM identities:
//  - softmax over size-1 axis == 1  =>  q,k,Wq,Wk dead; newV == v
//  - token j restarts from s0[:,j]; only cumV couples tokens
//  - prefix-sum linear => fold Wv into Wo: Wvo[a] = Wo[a] @ Wv[a] (once);
//       S1 = PS(LN1(T)) @ Wvo[a]^T + T
// R8 conclusion: GEMM-schedule space exhausted — serialized rocprof rank
// INVERTS vs graph E2E (ring-4 42us-serial -> E2E 1319; gemm_k 50.7 -> 1249);
// noise ~±30us. Anchor = R0 exactly. This round: Part partials fp32 -> bf16
// (sign-certain traffic cut: -50MB/stage, ~-60..85us), everything else R0.
// Pre-commit: absmax predicted 1.9-2.3 (thr 2.56); if >2.56 revert to fp32.

using bf16   = __bf16;
using bf16x8 = __attribute__((ext_vector_type(8))) __bf16;
using f32x4  = __attribute__((ext_vector_type(4))) float;

#define DEV __device__ __forceinline__

DEV void gload16(const bf16* g, bf16* l) {
  __builtin_amdgcn_global_load_lds(
      (const __attribute__((address_space(1))) unsigned int*)g,
      (__attribute__((address_space(3))) unsigned int*)l, 16, 0, 0);
}

// GELU with A&S 7.1.26 erf (abs err 1.5e-7; << bf16 rounding).
DEV float gelu_f(float x) {
  const float y  = x * 0.70710678118654752f;
  const float ay = fabsf(y);
  const float t  = __builtin_amdgcn_rcpf(__builtin_fmaf(0.3275911f, ay, 1.0f));
  float p = __builtin_fmaf(1.061405429f, t, -1.453152027f);
  p = __builtin_fmaf(p, t, 1.421413741f);
  p = __builtin_fmaf(p, t, -0.284496736f);
  p = __builtin_fmaf(p, t, 0.254829592f);
  p = p * t;
  const float e = __expf(-ay * ay);
  float er = __builtin_fmaf(-p, e, 1.0f);
  er = __builtin_copysignf(er, y);
  return 0.5f * x * (1.0f + er);
}

enum { EPI_PART = 0, EPI_GELU = 1, EPI_B16 = 2 };

// C[128 x BN tile] = A[M,K(+z*aZ)] @ B[N,K(+z*bZ)]^T over k in [z*kZ, z*kZ+klen).
// Exact R0 structure: XOR-swizzled LDS (2-way bank floor), double-buffered,
// ONE __syncthreads per K-iter (prefetch overlaps MFMA).
// EPI_PART now writes bf16 partials (outB + z*oZ).
template <int BN, int EPI>
__global__ __launch_bounds__(256) void gemm_k(
    const bf16* __restrict__ A, const bf16* __restrict__ B,
    bf16* __restrict__ outB, const float* __restrict__ aux, int K, int N,
    int kZ, int klen, size_t aZ, size_t bZ, size_t oZ)
{
  constexpr int ABUF = 128 * 32;
  constexpr int BBUF = BN * 32;
  __shared__ bf16 As[2 * ABUF];
  __shared__ bf16 Bs[2 * BBUF];
  const int z = blockIdx.z;
  A += (size_t)z * aZ;
  B += (size_t)z * bZ;
  const int kbeg = z * kZ;
  const int tid  = threadIdx.x;
  const int lane = tid & 63, wave = tid >> 6;
  const int m0 = blockIdx.x * 128, n0 = blockIdx.y * BN;

  // Staging: thread tid covers row r = tid>>2, physical slot tid&3.
  // Global chunk for that slot: kq = ((tid&3) - (r>>1)) & 3 — a permutation
  // within one aligned 64B line, so coalescing is preserved.
  const int r  = tid >> 2;
  const int kq = ((tid & 3) - (tid >> 3)) & 3;
  const bf16* aG0 = A + (size_t)(m0 + r) * K + kq * 8 + kbeg;
  const bf16* aG1 = aG0 + (size_t)64 * K;
  const bf16* bG0 = B + (size_t)(n0 + r) * K + kq * 8 + kbeg;
  const bf16* bG1 = bG0 + (size_t)64 * K;   // used only for BN==128

  const int wr = (wave & 1) * 64, wc = (wave >> 1) * (BN / 2);
  const int lr = lane & 15, kb = lane >> 4;
  const int swz  = ((kb + (lr >> 1)) & 3) * 8;
  const int aOff = (wr + lr) * 32 + swz;
  const int bOff = (wc + lr) * 32 + swz;

  constexpr int MT = 4, NT = BN / 32;
  f32x4 acc[MT][NT] = {};
  const int iters = klen >> 5;

  auto stage = [&](int p, int k0) {
    bf16* aD = &As[p * ABUF + tid * 8];
    gload16(aG0 + k0, aD);
    gload16(aG1 + k0, aD + 2048);
    bf16* bD = &Bs[p * BBUF + tid * 8];
    gload16(bG0 + k0, bD);
    if (BN == 128) gload16(bG1 + k0, bD + 2048);
  };

  stage(0, 0);
  for (int it = 0; it < iters; ++it) {
    __syncthreads();                       // drains vmcnt (cur tile arrived) + lgkm
    if (it + 1 < iters) stage((it + 1) & 1, (it + 1) * 32);  // overlaps MFMA below
    const int pa = (it & 1) * ABUF, pb = (it & 1) * BBUF;
    bf16x8 af[MT], bfv[NT];
#pragma unroll
    for (int t = 0; t < MT; ++t) af[t] = *(const bf16x8*)&As[pa + aOff + t * 512];
#pragma unroll
    for (int t = 0; t < NT; ++t) bfv[t] = *(const bf16x8*)&Bs[pb + bOff + t * 512];
#pragma unroll
    for (int mt = 0; mt < MT; ++mt)
#pragma unroll
      for (int nt = 0; nt < NT; ++nt)
        acc[mt][nt] = __builtin_amdgcn_mfma_f32_16x16x32_bf16(af[mt], bfv[nt], acc[mt][nt], 0, 0, 0);
  }

  // C/D layout: col = lane&15, row = (lane>>4)*4 + reg  [verified m89/m91]
  const int row0 = m0 + wr + (lane >> 4) * 4;
  const int col0 = n0 + wc + lr;
  bf16* oB = outB + (size_t)z * oZ;
#pragma unroll
  for (int mt = 0; mt < MT; ++mt) {
#pragma unroll
    for (int nt = 0; nt < NT; ++nt) {
      const int col = col0 + nt * 16;
      float bias = 0.f;
      if (EPI == EPI_GELU) bias = aux[col];
#pragma unroll
      for (int rg = 0; rg < 4; ++rg) {
        const int row = row0 + mt * 16 + rg;
        float v = acc[mt][nt][rg];
        if (EPI == EPI_GELU) {
          oB[(size_t)row * N + col] = (bf16)gelu_f(v + bias);
        } else {
          oB[(size_t)row * N + col] = (bf16)v;   // EPI_PART / EPI_B16
        }
      }
    }
  }
}

// One 768-row per block; sums NP split-K bf16 partials, adds per-MODE term,
// LN-fuses.
// MODE 0: s = Σp + PE[row&255]; T=s; SN = LN1(s)
// MODE 1: s = Σp + add[row]   ; SN = LN2(s)+s
// MODE 2: s = Σp + bias       ; T=s; SN = LN1(s)
// MODE 3: s = Σp + bias       ; T=s (fp32 out only, last stage)
template <int NP, int MODE>
__global__ __launch_bounds__(256) void reduce_ln(
    const bf16* __restrict__ P, size_t pZ,
    const float* __restrict__ add, const float* __restrict__ g,
    const float* __restrict__ b, float* __restrict__ Tout,
    bf16* __restrict__ SNout)
{
  const int row = blockIdx.x, t = threadIdx.x;
  float v[3];
#pragma unroll
  for (int c = 0; c < 3; ++c) {
    const int col = t + c * 256;
    float s = (float)P[(size_t)row * 768 + col];
#pragma unroll
    for (int p = 1; p < NP; ++p) s += (float)P[(size_t)p * pZ + (size_t)row * 768 + col];
    if (MODE == 0) s += add[(row & 255) * 768 + col];
    if (MODE == 1) s += add[(size_t)row * 768 + col];
    if (MODE == 2 || MODE == 3) s += add[col];
    v[c] = s;
  }
  if (MODE != 1) {
#pragma unroll
    for (int c = 0; c < 3; ++c) Tout[(size_t)row * 768 + t + c * 256] = v[c];
  }
  if (MODE == 3) return;

  __shared__ float red[8];
  float s = v[0] + v[1] + v[2];
#pragma unroll
  for (int o = 32; o >= 1; o >>= 1) s += __shfl_down(s, o);
  if ((t & 63) == 0) red[t >> 6] = s;
  __syncthreads();
  const float mu = (red[0] + red[1] + red[2] + red[3]) * (1.f / 768.f);
  const float d0 = v[0] - mu, d1 = v[1] - mu, d2 = v[2] - mu;
  float q = d0 * d0 + d1 * d1 + d2 * d2;
#pragma unroll
  for (int o = 32; o >= 1; o >>= 1) q += __shfl_down(q, o);
  if ((t & 63) == 0) red[4 + (t >> 6)] = q;
  __syncthreads();
  const float var = (red[4] + red[5] + red[6] + red[7]) * (1.f / 768.f);
  const float rs = rsqrtf(var + 1e-5f);
  float y0 = d0 * rs * g[t] + b[t];
  float y1 = d1 * rs * g[t + 256] + b[t + 256];
  float y2 = d2 * rs * g[t + 512] + b[t + 512];
  if (MODE == 1) { y0 += v[0]; y1 += v[1]; y2 += v[2]; }
  bf16* o = SNout + (size_t)row * 768;
  o[t] = (bf16)y0; o[t + 256] = (bf16)y1; o[t + 512] = (bf16)y2;
}

// Exclusive prefix over token axis j (256 tokens) of SN[n,j,d], bf16 io.
__global__ __launch_bounds__(256) void scan_partial_b(
    const bf16* __restrict__ SN, float* __restrict__ Ps)
{
  const int n = blockIdx.x, ch = blockIdx.y, d = blockIdx.z * 256 + threadIdx.x;
  const bf16* base = SN + ((size_t)(n * 256 + ch * 16)) * 768 + d;
  float s = 0.f;
#pragma unroll
  for (int j = 0; j < 16; ++j) s += (float)base[(size_t)j * 768];
  Ps[(size_t)(n * 16 + ch) * 768 + d] = s;
}

__global__ __launch_bounds__(256) void scan_final_b(
    const bf16* __restrict__ SN, const float* __restrict__ Ps,
    bf16* __restrict__ PSb)
{
  const int n = blockIdx.x, ch = blockIdx.y, d = blockIdx.z * 256 + threadIdx.x;
  float run = 0.f;
  for (int c = 0; c < ch; ++c) run += Ps[(size_t)(n * 16 + c) * 768 + d];
  const bf16* vb = SN + ((size_t)(n * 256 + ch * 16)) * 768 + d;
  bf16* ob = PSb + ((size_t)(n * 256 + ch * 16)) * 768 + d;
#pragma unroll
  for (int j = 0; j < 16; ++j) {
    ob[(size_t)j * 768] = (bf16)run;
    run += (float)vb[(size_t)j * 768];
  }
}

// WvT[a][n][k] = (bf16)Wv[a][k][n]; 64x64 tiles via LDS (65-float stride).
__global__ __launch_bounds__(256) void transpose_wv(
    const float* __restrict__ Wv, bf16* __restrict__ WvT)
{
  __shared__ float tile[64][65];
  const int a = blockIdx.z, k0 = blockIdx.x * 64, n0 = blockIdx.y * 64;
  const int c = threadIdx.x & 63, r4 = threadIdx.x >> 6;
  const float* src = Wv + (size_t)a * 589824;
  bf16* dst = WvT + (size_t)a * 589824;
#pragma unroll
  for (int i = 0; i < 16; ++i)
    tile[r4 + i * 4][c] = src[(size_t)(k0 + r4 + i * 4) * 768 + n0 + c];
  __syncthreads();
#pragma unroll
  for (int i = 0; i < 16; ++i) {
    const int n = r4 + i * 4;
    dst[(size_t)(n0 + n) * 768 + k0 + c] = (bf16)tile[c][n];
  }
}

__global__ __launch_bounds__(256) void f32_to_bf16_k(
    const float* __restrict__ in, bf16* __restrict__ out, int n4)
{
  const int i = blockIdx.x * 256 + threadIdx.x;
  if (i >= n4) return;
  const float4 v = ((const float4*)in)[i];
  bf16 h[4] = {(bf16)v.x, (bf16)v.y, (bf16)v.z, (bf16)v.w};
  *(uint2*)(out + 4 * (size_t)i) = *(uint2*)h;
}

// pe[j, 2p] = sin(j / 10000^(4p/768)),  pe[j, 2p+1] = cos(...)
__global__ __launch_bounds__(256) void pe_kernel(float* __restrict__ PE)
{
  const int id = blockIdx.x * 256 + threadIdx.x;  // 256*384 total
  const int j = id / 384, p = id % 384;
  const double ang = (double)j * pow(10000.0, -4.0 * (double)p / 768.0);
  PE[(size_t)j * 768 + 2 * p]     = (float)sin(ang);
  PE[(size_t)j * 768 + 2 * p + 1] = (float)cos(ang);
}

extern "C" void kernel_launch(void* const* d_in, const int* in_sizes, int n_in,
                              void* d_out, int out_size, void* d_ws, size_t ws_size,
                              hipStream_t stream)
{
  const float* x      = (const float*)d_in[0];
  const float* weight = (const float*)d_in[1];
  const float* Wv     = (const float*)d_in[4];
  const float* Wo     = (const float*)d_in[5];
  const float* ln1g   = (const float*)d_in[6];
  const float* ln1b   = (const float*)d_in[7];
  const float* ln2g   = (const float*)d_in[8];
  const float* ln2b   = (const float*)d_in[9];
  const float* fc1w   = (const float*)d_in[10];
  const float* fc1b   = (const float*)d_in[11];
  const float* fc2w   = (const float*)d_in[12];
  const float* fc2b   = (const float*)d_in[13];
  float* out = (float*)d_out;

  char* p = (char*)d_ws;
  auto alloc = [&](size_t bytes) { char* r = p; p += (bytes + 255) & ~(size_t)255; return r; };
  bf16*  Wb_w  = (bf16*)alloc(589824ull * 2);
  bf16*  Wb_o  = (bf16*)alloc(5898240ull * 2);
  bf16*  WvT   = (bf16*)alloc(5898240ull * 2);
  bf16*  Wvo   = (bf16*)alloc(5898240ull * 2);
  bf16*  Wb_f1 = (bf16*)alloc(2359296ull * 2);
  bf16*  Wb_f2 = (bf16*)alloc(2359296ull * 2);
  bf16*  Xb    = (bf16*)alloc(3145728ull * 2);
  float* PEf   = (float*)alloc(196608ull * 4);
  float* T     = (float*)alloc(3145728ull * 4);
  bf16*  SN    = (bf16*)alloc(3145728ull * 2);
  bf16*  PSb   = (bf16*)alloc(3145728ull * 2);
  bf16*  H     = (bf16*)alloc(12582912ull * 2);
  float* Ps    = (float*)alloc(196608ull * 4);
  bf16*  Part  = (bf16*)alloc(2ull * 3145728ull * 2);   // bf16 split-K partials

  auto cvt = [&](const float* src, bf16* dst, int n) {
    int n4 = n / 4;
    f32_to_bf16_k<<<(n4 + 255) / 256, 256, 0, stream>>>(src, dst, n4);
  };
  cvt(x, Xb, 3145728);
  cvt(weight, Wb_w, 589824);
  cvt(Wo, Wb_o, 5898240);
  cvt(fc1w, Wb_f1, 2359296);
  cvt(fc2w, Wb_f2, 2359296);
  transpose_wv<<<dim3(12, 12, 10), 256, 0, stream>>>(Wv, WvT);
  pe_kernel<<<384, 256, 0, stream>>>(PEf);

  // Wvo[a] = Wo[a] @ Wv[a]  (A = Wo[a][m,t], B = WvT[a][k,t], batched over z)
  gemm_k<128, EPI_B16><<<dim3(6, 6, 10), 256, 0, stream>>>(
      Wb_o, WvT, Wvo, nullptr, 768, 768, 0, 768, 589824, 589824, 589824);

  // T0 = x @ weight^T + PE (split-K x2, 128x64 tiles), fused LN1
  gemm_k<64, EPI_PART><<<dim3(32, 12, 2), 256, 0, stream>>>(
      Xb, Wb_w, Part, nullptr, 768, 768, 384, 384, 0, 0, 3145728);
  reduce_ln<2, 0><<<4096, 256, 0, stream>>>(Part, 3145728, PEf, ln1g, ln1b, T, SN);

  for (int a = 0; a < 10; ++a) {
    scan_partial_b<<<dim3(16, 16, 3), 256, 0, stream>>>(SN, Ps);
    scan_final_b<<<dim3(16, 16, 3), 256, 0, stream>>>(SN, Ps, PSb);
    // S1 partials = PS @ Wvo[a]^T  (split-K x2, 128x64 tiles)
    gemm_k<64, EPI_PART><<<dim3(32, 12, 2), 256, 0, stream>>>(
        PSb, Wvo + (size_t)a * 589824, Part, nullptr, 768, 768, 384, 384, 0, 0, 3145728);
    reduce_ln<2, 1><<<4096, 256, 0, stream>>>(Part, 3145728, T, ln2g, ln2b, nullptr, SN);
    // fc1: H = gelu(SN2 @ fc1w^T + b), 128x128 tiles (exact R0)
    gemm_k<128, EPI_GELU><<<dim3(32, 24, 1), 256, 0, stream>>>(
        SN, Wb_f1, H, fc1b, 768, 3072, 0, 768, 0, 0, 0);
    // fc2 partials: H @ fc2w^T (split-K x2, 128x64 tiles, exact R0 grid)
    gemm_k<64, EPI_PART><<<dim3(32, 12, 2), 256, 0, stream>>>(
        H, Wb_f2, Part, nullptr, 3072, 768, 1536, 1536, 0, 0, 3145728);
    if (a < 9)
      reduce_ln<2, 2><<<4096, 256, 0, stream>>>(Part, 3145728, fc2b, ln1g, ln1b, T, SN);
    else
      reduce_ln<2, 3><<<4096, 256, 0, stream>>>(Part, 3145728, fc2b, nullptr, nullptr, out, nullptr);
  }
  (void)in_sizes; (void)n_in; (void)out_size; (void)ws_size;
}